// Round 9
// baseline (242.217 us; speedup 1.0000x reference)
//
#include <hip/hip_runtime.h>
#include <stdint.h>

// Problem constants
constexpr int NBATCH = 4;
constexpr int CH     = 256;   // channels
constexpr int LEN    = 4096;  // sequence length
constexpr int LPOOL  = 1024;  // pooled length (LEN/4)
constexpr int NH     = 4;     // heads
constexpr int HD     = 64;    // head dim

typedef __attribute__((ext_vector_type(8))) short short8;   // 8 bf16 in 4 VGPRs
typedef __attribute__((ext_vector_type(4))) float float4e;  // MFMA C/D

__device__ __forceinline__ unsigned short f2bf(float f) {
    union { unsigned int i; float f; } v; v.f = f;
    unsigned int lsb = (v.i >> 16) & 1u;
    v.i += 0x7fffu + lsb;
    return (unsigned short)(v.i >> 16);
}
// pack two floats -> two bf16 (round-half-up via +0x8000, then byte-perm)
__device__ __forceinline__ unsigned pack2bf(float lo, float hi) {
    unsigned a = __float_as_uint(lo) + 0x8000u;
    unsigned b = __float_as_uint(hi) + 0x8000u;
    return __builtin_amdgcn_perm(b, a, 0x07060302u);
}

// ---------------------------------------------------------------------------
// Fused: blocks 0..1023 do transpose+pool over x; blocks 1024..1343 cast the
// 5 weight matrices to bf16; block 1344 computes BN affine + bkv concat.
__global__ __launch_bounds__(256) void transpool_setup(
    const float* __restrict__ x, unsigned short* __restrict__ xbf,
    unsigned short* __restrict__ poolT,
    const float* __restrict__ w0, const float* __restrict__ w1,
    const float* __restrict__ w2, const float* __restrict__ w3,
    const float* __restrict__ w4, unsigned short* __restrict__ outW,
    const float* __restrict__ g1, const float* __restrict__ b1,
    const float* __restrict__ m1, const float* __restrict__ v1,
    const float* __restrict__ g2, const float* __restrict__ b2,
    const float* __restrict__ m2, const float* __restrict__ v2,
    float* __restrict__ scale, float* __restrict__ shift,
    const float* __restrict__ bk, const float* __restrict__ bv,
    float* __restrict__ bkv)
{
    __shared__ float T[64][65];
    __shared__ float P16[64][17];
    int b = blockIdx.x, t = threadIdx.x;
    if (b >= 1024) {
        int sb = b - 1024;
        if (sb < 320) {
            int gid = sb * 256 + t;
            int w = gid >> 14;
            int off = (gid & 16383) * 4;
            const float* src = (w == 0) ? w0 : (w == 1) ? w1 : (w == 2) ? w2 : (w == 3) ? w3 : w4;
            float4 v = *(const float4*)(src + off);
            uint2 pk;
            pk.x = pack2bf(v.x, v.y);
            pk.y = pack2bf(v.z, v.w);
            *(uint2*)(outW + w * 65536 + off) = pk;
        } else {
            float inv1 = g1[t] * rsqrtf(v1[t] + 1e-5f);
            float inv2 = g2[t] * rsqrtf(v2[t] + 1e-5f);
            scale[t] = inv1 * inv2;
            shift[t] = (b1[t] - m1[t] * inv1) * inv2 + (b2[t] - m2[t] * inv2);
            bkv[t] = bk[t];
            bkv[256 + t] = bv[t];
        }
        return;
    }
    int n = b >> 8, c0 = ((b >> 6) & 3) * 64, l0 = (b & 63) * 64;
    const float* xp = x + ((size_t)n * CH + c0) * LEN + l0;
    #pragma unroll
    for (int i = 0; i < 4; i++) {
        int idx = t + i * 256;
        int c = idx >> 4, l4 = idx & 15;
        float4 v = *(const float4*)(xp + (size_t)c * LEN + l4 * 4);
        T[c][l4 * 4 + 0] = v.x; T[c][l4 * 4 + 1] = v.y;
        T[c][l4 * 4 + 2] = v.z; T[c][l4 * 4 + 3] = v.w;
        P16[c][l4] = (v.x + v.y + v.z + v.w) * 0.25f
                   + fmaxf(fmaxf(v.x, v.y), fmaxf(v.z, v.w));
    }
    __syncthreads();
    unsigned short* op = xbf + ((size_t)n * LEN + l0) * CH + c0;
    #pragma unroll
    for (int i = 0; i < 4; i++) {
        int idx = t + i * 256;
        int l = idx >> 4, c4 = idx & 15;
        uint2 pk;
        pk.x = pack2bf(T[c4 * 4 + 0][l], T[c4 * 4 + 1][l]);
        pk.y = pack2bf(T[c4 * 4 + 2][l], T[c4 * 4 + 3][l]);
        *(uint2*)(op + (size_t)l * CH + c4 * 4) = pk;
    }
    int p0 = l0 >> 2;
    #pragma unroll
    for (int k = 0; k < 2; k++) {
        int p = (t >> 5) + k * 8;
        int c2 = (t & 31) * 2;
        unsigned pk = pack2bf(P16[c2][p], P16[c2 + 1][p]);
        *(unsigned*)(poolT + ((size_t)n * LPOOL + p0 + p) * CH + c0 + c2) = pk;
    }
}

// ---------------------------------------------------------------------------
// MFMA GEMM: D[i][j] = sum_k A[i][k] * B[j][k], K = 256 (bf16, K-contig rows).
// Epilogue: + biasRow[i]; *scale[i]+shift[i]; *outScale.
// Output modes (per 128-row tile):
//   outF != 0                : f32 [row][col] (ld NN), LDS-restaged 512B stores
//   rowTile <  rowSplit      : bf16 at out1 + col*cs1 + row  (column-major-ish)
//   rowTile >= rowSplit      : bf16 at out2 + (row-rowSplit)*rs2 + col
__global__ __launch_bounds__(256) void gemm_mfma(
    const unsigned short* __restrict__ A,
    const unsigned short* __restrict__ B, size_t bBatch,
    const float* __restrict__ biasRow,
    const float* __restrict__ scale, const float* __restrict__ shift,
    float* __restrict__ outF, size_t oFBatch,
    unsigned short* __restrict__ out1, size_t o1Batch, int cs1,
    unsigned short* __restrict__ out2, size_t o2Batch, int rs2, int rowSplit,
    int NN, float outScale)
{
    __shared__ unsigned short smem[2 * 128 * 72];  // As | Bs ; reused for epilogue
    unsigned short* As = smem;
    unsigned short* Bs = smem + 128 * 72;

    int n = blockIdx.z;
    int t = threadIdx.x;
    int wave = t >> 6, lane = t & 63, m = lane & 15, quad = lane >> 4;
    int wm = wave & 1, wn = wave >> 1;
    int rowTile = blockIdx.y * 128;
    int col0 = blockIdx.x * 128;

    const unsigned short* Ab = A + (size_t)rowTile * 256;
    const unsigned short* Bb = B + (size_t)n * bBatch + (size_t)col0 * 256;

    float4e acc[4][4] = {};

    for (int kk = 0; kk < 256; kk += 64) {
        #pragma unroll
        for (int i = 0; i < 4; i++) {
            int idx = t + i * 256;
            int row = idx >> 3, ch = idx & 7;
            *(uint4*)&As[row * 72 + ch * 8] = *(const uint4*)(Ab + (size_t)row * 256 + kk + ch * 8);
            *(uint4*)&Bs[row * 72 + ch * 8] = *(const uint4*)(Bb + (size_t)row * 256 + kk + ch * 8);
        }
        __syncthreads();
        #pragma unroll
        for (int kc = 0; kc < 2; kc++) {
            short8 af[4], bfr[4];
            #pragma unroll
            for (int i = 0; i < 4; i++)
                af[i] = *(const short8*)&As[(wm * 64 + i * 16 + m) * 72 + kc * 32 + quad * 8];
            #pragma unroll
            for (int j = 0; j < 4; j++)
                bfr[j] = *(const short8*)&Bs[(wn * 64 + j * 16 + m) * 72 + kc * 32 + quad * 8];
            #pragma unroll
            for (int i = 0; i < 4; i++)
                #pragma unroll
                for (int j = 0; j < 4; j++)
                    acc[i][j] = __builtin_amdgcn_mfma_f32_16x16x32_bf16(af[i], bfr[j], acc[i][j], 0, 0, 0);
        }
        __syncthreads();
    }

    if (outF) {
        // fp32 output, restaged through LDS in two 64-row halves
        float* TOf = (float*)smem;   // [64][128]
        float* dst = outF + (size_t)n * oFBatch;
        #pragma unroll
        for (int half = 0; half < 2; half++) {
            __syncthreads();
            if (wm == half) {
                #pragma unroll
                for (int i = 0; i < 4; i++) {
                    int rowL = i * 16 + quad * 4;
                    int rowG = rowTile + half * 64 + rowL;
                    float br[4], sc[4], sh[4];
                    #pragma unroll
                    for (int r = 0; r < 4; r++) {
                        br[r] = biasRow ? biasRow[rowG + r] : 0.0f;
                        sc[r] = scale ? scale[rowG + r] : 1.0f;
                        sh[r] = shift ? shift[rowG + r] : 0.0f;
                    }
                    #pragma unroll
                    for (int j = 0; j < 4; j++) {
                        int colL = wn * 64 + j * 16 + m;
                        float4e c = acc[i][j];
                        #pragma unroll
                        for (int r = 0; r < 4; r++)
                            TOf[(rowL + r) * 128 + colL] = ((c[r] + br[r]) * sc[r] + sh[r]) * outScale;
                    }
                }
            }
            __syncthreads();
            #pragma unroll
            for (int w = 0; w < 8; w++) {
                int idx = t + w * 256;
                int row = idx >> 5, c4 = idx & 31;
                *(float4*)(dst + (size_t)(rowTile + half * 64 + row) * NN + col0 + c4 * 4) =
                    *(const float4*)&TOf[row * 128 + c4 * 4];
            }
        }
        return;
    }

    bool mode2 = (rowTile >= rowSplit);
    unsigned short* TO = smem;
    #pragma unroll
    for (int i = 0; i < 4; i++) {
        int rowL = wm * 64 + i * 16 + quad * 4;
        int rowG = rowTile + rowL;
        float br[4], sc[4], sh[4];
        #pragma unroll
        for (int r = 0; r < 4; r++) {
            br[r] = biasRow ? biasRow[rowG + r] : 0.0f;
            sc[r] = scale ? scale[rowG + r] : 1.0f;
            sh[r] = shift ? shift[rowG + r] : 0.0f;
        }
        #pragma unroll
        for (int j = 0; j < 4; j++) {
            int colL = wn * 64 + j * 16 + m;
            float4e c = acc[i][j];
            float v0 = ((c[0] + br[0]) * sc[0] + sh[0]) * outScale;
            float v1 = ((c[1] + br[1]) * sc[1] + sh[1]) * outScale;
            float v2 = ((c[2] + br[2]) * sc[2] + sh[2]) * outScale;
            float v3 = ((c[3] + br[3]) * sc[3] + sh[3]) * outScale;
            if (!mode2) {
                uint2 pk;
                pk.x = pack2bf(v0, v1);
                pk.y = pack2bf(v2, v3);
                *(uint2*)&TO[colL * 136 + rowL] = pk;
            } else {
                TO[(rowL + 0) * 136 + colL] = f2bf(v0);
                TO[(rowL + 1) * 136 + colL] = f2bf(v1);
                TO[(rowL + 2) * 136 + colL] = f2bf(v2);
                TO[(rowL + 3) * 136 + colL] = f2bf(v3);
            }
        }
    }
    __syncthreads();
    if (!mode2) {
        unsigned short* dst = out1 + (size_t)n * o1Batch;
        #pragma unroll
        for (int w = 0; w < 8; w++) {
            int idx = t + w * 256;
            int l = idx >> 4, ch = idx & 15;
            *(uint4*)(dst + (size_t)(col0 + l) * cs1 + rowTile + ch * 8) =
                *(const uint4*)&TO[l * 136 + ch * 8];
        }
    } else {
        unsigned short* dst = out2 + (size_t)n * o2Batch;
        int rowBase = rowTile - rowSplit;
        #pragma unroll
        for (int w = 0; w < 8; w++) {
            int idx = t + w * 256;
            int row = idx >> 4, ch = idx & 15;
            *(uint4*)(dst + (size_t)(rowBase + row) * rs2 + col0 + ch * 8) =
                *(const uint4*)&TO[row * 136 + ch * 8];
        }
    }
}

// ---------------------------------------------------------------------------
// MFMA flash attention, fixed-shift softmax, register-resident P, SPLIT-K.
// 512 threads = 8 waves: waves 0-3 (grp 0) process keys 0..511, waves 4-7
// (grp 1) keys 512..1023, same 128 q rows. Fixed-shift softmax makes the
// partials additive: Oa_tot = Oa0 + Oa1, l_tot = l0 + l1 (combined via LDS).
// PV MFMA's k->key mapping matches P's C-layout (see r8) so P never leaves
// registers. Qb: [N,L,C] bf16 (pre-scaled log2(e)/8); Kb: [N,L2,C];
// Vb: [N,C,L2]; Obf: [N,L,C] bf16 (O^T layout, feeds o-proj as B operand).
__global__ __launch_bounds__(512, 4) void attn_mfma(
    const unsigned short* __restrict__ Qb,
    const unsigned short* __restrict__ Kb,
    const unsigned short* __restrict__ Vb,
    unsigned short* __restrict__ Obf)
{
    __shared__ unsigned short Ks[2][128 * 72];   // per-group K-tile [key][e]
    __shared__ unsigned short Vs[2][64 * 136];   // per-group V^T-tile [e][key]

    int qb = blockIdx.x;
    int h  = blockIdx.y;
    int n  = blockIdx.z;
    int t  = threadIdx.x;
    int wave = t >> 6, lane = t & 63;
    int grp = wave >> 2;          // 0: keys 0-511, 1: keys 512-1023
    int wq  = wave & 3;           // q sub-block within the 128
    int m = lane & 15, quad = lane >> 4;
    int l0 = qb * 128 + wq * 32;

    const unsigned short* qp = Qb + ((size_t)n * LEN + l0 + m) * CH + h * HD + quad * 8;
    short8 bQ[2][2];
    bQ[0][0] = *(const short8*)qp;
    bQ[0][1] = *(const short8*)(qp + 32);
    bQ[1][0] = *(const short8*)(qp + 16 * CH);
    bQ[1][1] = *(const short8*)(qp + 16 * CH + 32);

    float4e Oa[2][4] = {};
    float l_run[2] = {0.0f, 0.0f};

    const unsigned short* KgBase = Kb + (size_t)n * LPOOL * CH + h * HD;
    const unsigned short* VgBase = Vb + ((size_t)n * CH + h * HD) * LPOOL;
    const float NEG = -17.312340f;   // -12 * log2(e)

    for (int kt = 0; kt < 4; kt++) {
        __syncthreads();   // previous iteration's readers done
        {
            // 512 threads stage both groups' tiles: thread t>>8 picks half
            int hb = t >> 8, tt = t & 255;
            int ktG = hb * 4 + kt;
            const unsigned short* Kg = KgBase + (size_t)ktG * 128 * CH;
            const unsigned short* Vg = VgBase + ktG * 128;
            #pragma unroll
            for (int i = 0; i < 4; i++) {
                int idx = tt + i * 256;
                *(uint4*)&Ks[hb][(idx >> 3) * 72 + (idx & 7) * 8] =
                    *(const uint4*)(Kg + (size_t)(idx >> 3) * CH + (idx & 7) * 8);
                *(uint4*)&Vs[hb][(idx >> 4) * 136 + (idx & 15) * 8] =
                    *(const uint4*)(Vg + (size_t)(idx >> 4) * LPOOL + (idx & 15) * 8);
            }
        }
        __syncthreads();

        // 4 chunks of 32 keys: QK (2 subtiles) -> exp2 -> in-register P -> PV
        #pragma unroll
        for (int ch2 = 0; ch2 < 4; ch2++) {
            const unsigned short* kpE = &Ks[grp][(ch2 * 32 + m) * 72 + quad * 8];
            const unsigned short* kpO = kpE + 16 * 72;
            short8 aE0 = *(const short8*)kpE;
            short8 aE1 = *(const short8*)(kpE + 32);
            short8 aO0 = *(const short8*)kpO;
            short8 aO1 = *(const short8*)(kpO + 32);
            union { unsigned u[4]; short8 s; } aV[4];
            #pragma unroll
            for (int eb = 0; eb < 4; eb++) {
                const unsigned short* vp = &Vs[grp][(eb * 16 + m) * 136 + ch2 * 32 + quad * 4];
                *(uint2*)&aV[eb].u[0] = *(const uint2*)vp;
                *(uint2*)&aV[eb].u[2] = *(const uint2*)(vp + 16);
            }

            #pragma unroll
            for (int qf = 0; qf < 2; qf++) {
                float4e cE = {NEG, NEG, NEG, NEG};
                cE = __builtin_amdgcn_mfma_f32_16x16x32_bf16(aE0, bQ[qf][0], cE, 0, 0, 0);
                cE = __builtin_amdgcn_mfma_f32_16x16x32_bf16(aE1, bQ[qf][1], cE, 0, 0, 0);
                float4e cO = {NEG, NEG, NEG, NEG};
                cO = __builtin_amdgcn_mfma_f32_16x16x32_bf16(aO0, bQ[qf][0], cO, 0, 0, 0);
                cO = __builtin_amdgcn_mfma_f32_16x16x32_bf16(aO1, bQ[qf][1], cO, 0, 0, 0);
                float pE0 = exp2f(cE[0]), pE1 = exp2f(cE[1]);
                float pE2 = exp2f(cE[2]), pE3 = exp2f(cE[3]);
                float pO0 = exp2f(cO[0]), pO1 = exp2f(cO[1]);
                float pO2 = exp2f(cO[2]), pO3 = exp2f(cO[3]);
                l_run[qf] += ((pE0 + pE1) + (pE2 + pE3)) + ((pO0 + pO1) + (pO2 + pO3));
                union { unsigned u[4]; short8 s; } bP;
                bP.u[0] = pack2bf(pE0, pE1);
                bP.u[1] = pack2bf(pE2, pE3);
                bP.u[2] = pack2bf(pO0, pO1);
                bP.u[3] = pack2bf(pO2, pO3);
                #pragma unroll
                for (int eb = 0; eb < 4; eb++)
                    Oa[qf][eb] = __builtin_amdgcn_mfma_f32_16x16x32_bf16(aV[eb].s, bP.s, Oa[qf][eb], 0, 0, 0);
            }
        }
    }

    // combine the two key-halves via LDS (reuse Ks area; 34 KB needed)
    __syncthreads();
    float* Cb = (float*)&Ks[0][0];
    int base = (wq * 64 + lane) * 34;
    if (grp == 1) {
        #pragma unroll
        for (int qf = 0; qf < 2; qf++)
            #pragma unroll
            for (int eb = 0; eb < 4; eb++)
                *(float4*)&Cb[base + (qf * 4 + eb) * 4] = *(float4*)&Oa[qf][eb];
        Cb[base + 32] = l_run[0];
        Cb[base + 33] = l_run[1];
    }
    __syncthreads();
    if (grp == 0) {
        #pragma unroll
        for (int qf = 0; qf < 2; qf++) {
            #pragma unroll
            for (int eb = 0; eb < 4; eb++) {
                float4 o = *(const float4*)&Cb[base + (qf * 4 + eb) * 4];
                Oa[qf][eb][0] += o.x; Oa[qf][eb][1] += o.y;
                Oa[qf][eb][2] += o.z; Oa[qf][eb][3] += o.w;
            }
        }
        l_run[0] += Cb[base + 32];
        l_run[1] += Cb[base + 33];

        #pragma unroll
        for (int qf = 0; qf < 2; qf++) {
            float l = l_run[qf];
            l += __shfl_xor(l, 16);
            l += __shfl_xor(l, 32);
            float inv = 1.0f / l;
            unsigned short* op = Obf + ((size_t)n * LEN + l0 + qf * 16 + m) * CH + h * HD;
            #pragma unroll
            for (int eb = 0; eb < 4; eb++) {
                uint2 pk;
                pk.x = pack2bf(Oa[qf][eb][0] * inv, Oa[qf][eb][1] * inv);
                pk.y = pack2bf(Oa[qf][eb][2] * inv, Oa[qf][eb][3] * inv);
                *(uint2*)(op + eb * 16 + quad * 4) = pk;
            }
        }
    }
}

// ---------------------------------------------------------------------------
extern "C" void kernel_launch(void* const* d_in, const int* in_sizes, int n_in,
                              void* d_out, int out_size, void* d_ws, size_t ws_size,
                              hipStream_t stream)
{
    const float* x  = (const float*)d_in[0];
    const float* Wq = (const float*)d_in[1];
    const float* bq = (const float*)d_in[2];
    const float* Wk = (const float*)d_in[3];
    const float* bk = (const float*)d_in[4];
    const float* Wv = (const float*)d_in[5];
    const float* bv = (const float*)d_in[6];
    const float* Wo = (const float*)d_in[7];
    const float* bo = (const float*)d_in[8];
    const float* Wa = (const float*)d_in[9];
    const float* g1 = (const float*)d_in[10];
    const float* b1 = (const float*)d_in[11];
    const float* m1 = (const float*)d_in[12];
    const float* v1 = (const float*)d_in[13];
    const float* g2 = (const float*)d_in[14];
    const float* b2 = (const float*)d_in[15];
    const float* m2 = (const float*)d_in[16];
    const float* v2 = (const float*)d_in[17];

    float* wsf      = (float*)d_ws;
    float* bn_scale = wsf;            // 256
    float* bn_shift = wsf + 256;      // 256
    float* bkv      = wsf + 512;      // 512
    unsigned short* Wbf   = (unsigned short*)(wsf + 1024);          // 5*65536
    unsigned short* xbf   = Wbf + 5 * 65536;                        // [N,L,C]
    unsigned short* poolT = xbf   + (size_t)NBATCH * LEN * CH;      // [N,L2,C]
    unsigned short* xabf  = poolT + (size_t)NBATCH * LPOOL * CH;    // [N,L2,C]
    unsigned short* Kbf   = xabf  + (size_t)NBATCH * LPOOL * CH;    // [N,L2,C]
    unsigned short* Vbf   = Kbf   + (size_t)NBATCH * LPOOL * CH;    // [N,C,L2]
    unsigned short* Qbf   = Vbf   + (size_t)NBATCH * LPOOL * CH;    // [N,L,C]
    unsigned short* Obf   = Qbf   + (size_t)NBATCH * LEN * CH;      // [N,L,C]

    // 1. transpose+pool over x, weights->bf16, BN affine, bkv concat
    transpool_setup<<<1345, 256, 0, stream>>>(x, xbf, poolT,
        Wq, Wk, Wv, Wo, Wa, Wbf,
        g1, b1, m1, v1, g2, b2, m2, v2, bn_scale, bn_shift, bk, bv, bkv);

    // 2. q = Wq @ x + bq, pre-scaled by log2(e)/8 -> Qbf [N,L,C]
    gemm_mfma<<<dim3(32, 2, 4), 256, 0, stream>>>(
        Wbf + 0 * 65536, xbf, (size_t)LEN * CH, bq, nullptr, nullptr,
        nullptr, 0, Qbf, (size_t)LEN * CH, 256, nullptr, 0, 0, 1 << 30,
        LEN, 0.18033688f);

    // 3. xa = BN2(BN1(Wa @ pool(x))) -> xabf [N,L2,C]
    gemm_mfma<<<dim3(8, 2, 4), 256, 0, stream>>>(
        Wbf + 4 * 65536, poolT, (size_t)LPOOL * CH, nullptr, bn_scale, bn_shift,
        nullptr, 0, xabf, (size_t)LPOOL * CH, 256, nullptr, 0, 0, 1 << 30,
        LPOOL, 1.0f);

    // 4. fused k+v: A = [Wk;Wv] (contiguous in Wbf), M=512.
    //    rows 0..255 -> Kbf [l2][c] (mode1); rows 256..511 -> Vbf [c][l2] (mode2)
    gemm_mfma<<<dim3(8, 4, 4), 256, 0, stream>>>(
        Wbf + 1 * 65536, xabf, (size_t)LPOOL * CH, bkv, nullptr, nullptr,
        nullptr, 0, Kbf, (size_t)LPOOL * CH, 256, Vbf, (size_t)LPOOL * CH, LPOOL, 256,
        LPOOL, 1.0f);

    // 5. attention -> Obf [N,L,C] bf16  (512-thread split-K blocks)
    attn_mfma<<<dim3(LEN / 128, NH, NBATCH), 512, 0, stream>>>(Qbf, Kbf, Vbf, Obf);

    // 6. out = Wo @ o + bo -> f32 d_out [N,C,L]
    gemm_mfma<<<dim3(32, 2, 4), 256, 0, stream>>>(
        Wbf + 3 * 65536, Obf, (size_t)LEN * CH, bo, nullptr, nullptr,
        (float*)d_out, (size_t)CH * LEN, nullptr, 0, 0, nullptr, 0, 0, 1 << 30,
        LEN, 1.0f);
}

// Round 10
// 182.052 us; speedup vs baseline: 1.3305x; 1.3305x over previous
//
#include <hip/hip_runtime.h>
#include <stdint.h>

// Problem constants
constexpr int NBATCH = 4;
constexpr int CH     = 256;   // channels
constexpr int LEN    = 4096;  // sequence length
constexpr int LPOOL  = 1024;  // pooled length (LEN/4)
constexpr int NH     = 4;     // heads
constexpr int HD     = 64;    // head dim

typedef __attribute__((ext_vector_type(8))) short short8;   // 8 bf16 in 4 VGPRs
typedef __attribute__((ext_vector_type(4))) float float4e;  // MFMA C/D

__device__ __forceinline__ unsigned short f2bf(float f) {
    union { unsigned int i; float f; } v; v.f = f;
    unsigned int lsb = (v.i >> 16) & 1u;
    v.i += 0x7fffu + lsb;
    return (unsigned short)(v.i >> 16);
}
// pack two floats -> two bf16 (round-half-up via +0x8000, then byte-perm)
__device__ __forceinline__ unsigned pack2bf(float lo, float hi) {
    unsigned a = __float_as_uint(lo) + 0x8000u;
    unsigned b = __float_as_uint(hi) + 0x8000u;
    return __builtin_amdgcn_perm(b, a, 0x07060302u);
}

// ---------------------------------------------------------------------------
// Fused: blocks 0..1023 do transpose+pool over x; blocks 1024..1343 cast the
// 5 weight matrices to bf16; block 1344 computes BN affine + bkv concat.
__global__ __launch_bounds__(256) void transpool_setup(
    const float* __restrict__ x, unsigned short* __restrict__ xbf,
    unsigned short* __restrict__ poolT,
    const float* __restrict__ w0, const float* __restrict__ w1,
    const float* __restrict__ w2, const float* __restrict__ w3,
    const float* __restrict__ w4, unsigned short* __restrict__ outW,
    const float* __restrict__ g1, const float* __restrict__ b1,
    const float* __restrict__ m1, const float* __restrict__ v1,
    const float* __restrict__ g2, const float* __restrict__ b2,
    const float* __restrict__ m2, const float* __restrict__ v2,
    float* __restrict__ scale, float* __restrict__ shift,
    const float* __restrict__ bk, const float* __restrict__ bv,
    float* __restrict__ bkv)
{
    __shared__ float T[64][65];
    __shared__ float P16[64][17];
    int b = blockIdx.x, t = threadIdx.x;
    if (b >= 1024) {
        int sb = b - 1024;
        if (sb < 320) {
            int gid = sb * 256 + t;
            int w = gid >> 14;
            int off = (gid & 16383) * 4;
            const float* src = (w == 0) ? w0 : (w == 1) ? w1 : (w == 2) ? w2 : (w == 3) ? w3 : w4;
            float4 v = *(const float4*)(src + off);
            uint2 pk;
            pk.x = pack2bf(v.x, v.y);
            pk.y = pack2bf(v.z, v.w);
            *(uint2*)(outW + w * 65536 + off) = pk;
        } else {
            float inv1 = g1[t] * rsqrtf(v1[t] + 1e-5f);
            float inv2 = g2[t] * rsqrtf(v2[t] + 1e-5f);
            scale[t] = inv1 * inv2;
            shift[t] = (b1[t] - m1[t] * inv1) * inv2 + (b2[t] - m2[t] * inv2);
            bkv[t] = bk[t];
            bkv[256 + t] = bv[t];
        }
        return;
    }
    int n = b >> 8, c0 = ((b >> 6) & 3) * 64, l0 = (b & 63) * 64;
    const float* xp = x + ((size_t)n * CH + c0) * LEN + l0;
    #pragma unroll
    for (int i = 0; i < 4; i++) {
        int idx = t + i * 256;
        int c = idx >> 4, l4 = idx & 15;
        float4 v = *(const float4*)(xp + (size_t)c * LEN + l4 * 4);
        T[c][l4 * 4 + 0] = v.x; T[c][l4 * 4 + 1] = v.y;
        T[c][l4 * 4 + 2] = v.z; T[c][l4 * 4 + 3] = v.w;
        P16[c][l4] = (v.x + v.y + v.z + v.w) * 0.25f
                   + fmaxf(fmaxf(v.x, v.y), fmaxf(v.z, v.w));
    }
    __syncthreads();
    unsigned short* op = xbf + ((size_t)n * LEN + l0) * CH + c0;
    #pragma unroll
    for (int i = 0; i < 4; i++) {
        int idx = t + i * 256;
        int l = idx >> 4, c4 = idx & 15;
        uint2 pk;
        pk.x = pack2bf(T[c4 * 4 + 0][l], T[c4 * 4 + 1][l]);
        pk.y = pack2bf(T[c4 * 4 + 2][l], T[c4 * 4 + 3][l]);
        *(uint2*)(op + (size_t)l * CH + c4 * 4) = pk;
    }
    int p0 = l0 >> 2;
    #pragma unroll
    for (int k = 0; k < 2; k++) {
        int p = (t >> 5) + k * 8;
        int c2 = (t & 31) * 2;
        unsigned pk = pack2bf(P16[c2][p], P16[c2 + 1][p]);
        *(unsigned*)(poolT + ((size_t)n * LPOOL + p0 + p) * CH + c0 + c2) = pk;
    }
}

// ---------------------------------------------------------------------------
// MFMA GEMM: D[i][j] = sum_k A[i][k] * B[j][k], K = 256 (bf16, K-contig rows).
// Epilogue: + biasRow[i]; *scale[i]+shift[i]; *outScale.
// Output modes (per 128-row tile):
//   outF != 0                : f32 [row][col] (ld NN), LDS-restaged 512B stores
//   rowTile <  rowSplit      : bf16 at out1 + col*cs1 + row  (column-major-ish)
//   rowTile >= rowSplit      : bf16 at out2 + (row-rowSplit)*rs2 + col
__global__ __launch_bounds__(256) void gemm_mfma(
    const unsigned short* __restrict__ A,
    const unsigned short* __restrict__ B, size_t bBatch,
    const float* __restrict__ biasRow,
    const float* __restrict__ scale, const float* __restrict__ shift,
    float* __restrict__ outF, size_t oFBatch,
    unsigned short* __restrict__ out1, size_t o1Batch, int cs1,
    unsigned short* __restrict__ out2, size_t o2Batch, int rs2, int rowSplit,
    int NN, float outScale)
{
    __shared__ unsigned short smem[2 * 128 * 72];  // As | Bs ; reused for epilogue
    unsigned short* As = smem;
    unsigned short* Bs = smem + 128 * 72;

    int n = blockIdx.z;
    int t = threadIdx.x;
    int wave = t >> 6, lane = t & 63, m = lane & 15, quad = lane >> 4;
    int wm = wave & 1, wn = wave >> 1;
    int rowTile = blockIdx.y * 128;
    int col0 = blockIdx.x * 128;

    const unsigned short* Ab = A + (size_t)rowTile * 256;
    const unsigned short* Bb = B + (size_t)n * bBatch + (size_t)col0 * 256;

    float4e acc[4][4] = {};

    for (int kk = 0; kk < 256; kk += 64) {
        #pragma unroll
        for (int i = 0; i < 4; i++) {
            int idx = t + i * 256;
            int row = idx >> 3, ch = idx & 7;
            *(uint4*)&As[row * 72 + ch * 8] = *(const uint4*)(Ab + (size_t)row * 256 + kk + ch * 8);
            *(uint4*)&Bs[row * 72 + ch * 8] = *(const uint4*)(Bb + (size_t)row * 256 + kk + ch * 8);
        }
        __syncthreads();
        #pragma unroll
        for (int kc = 0; kc < 2; kc++) {
            short8 af[4], bfr[4];
            #pragma unroll
            for (int i = 0; i < 4; i++)
                af[i] = *(const short8*)&As[(wm * 64 + i * 16 + m) * 72 + kc * 32 + quad * 8];
            #pragma unroll
            for (int j = 0; j < 4; j++)
                bfr[j] = *(const short8*)&Bs[(wn * 64 + j * 16 + m) * 72 + kc * 32 + quad * 8];
            #pragma unroll
            for (int i = 0; i < 4; i++)
                #pragma unroll
                for (int j = 0; j < 4; j++)
                    acc[i][j] = __builtin_amdgcn_mfma_f32_16x16x32_bf16(af[i], bfr[j], acc[i][j], 0, 0, 0);
        }
        __syncthreads();
    }

    if (outF) {
        // fp32 output, restaged through LDS in two 64-row halves
        float* TOf = (float*)smem;   // [64][128]
        float* dst = outF + (size_t)n * oFBatch;
        #pragma unroll
        for (int half = 0; half < 2; half++) {
            __syncthreads();
            if (wm == half) {
                #pragma unroll
                for (int i = 0; i < 4; i++) {
                    int rowL = i * 16 + quad * 4;
                    int rowG = rowTile + half * 64 + rowL;
                    float br[4], sc[4], sh[4];
                    #pragma unroll
                    for (int r = 0; r < 4; r++) {
                        br[r] = biasRow ? biasRow[rowG + r] : 0.0f;
                        sc[r] = scale ? scale[rowG + r] : 1.0f;
                        sh[r] = shift ? shift[rowG + r] : 0.0f;
                    }
                    #pragma unroll
                    for (int j = 0; j < 4; j++) {
                        int colL = wn * 64 + j * 16 + m;
                        float4e c = acc[i][j];
                        #pragma unroll
                        for (int r = 0; r < 4; r++)
                            TOf[(rowL + r) * 128 + colL] = ((c[r] + br[r]) * sc[r] + sh[r]) * outScale;
                    }
                }
            }
            __syncthreads();
            #pragma unroll
            for (int w = 0; w < 8; w++) {
                int idx = t + w * 256;
                int row = idx >> 5, c4 = idx & 31;
                *(float4*)(dst + (size_t)(rowTile + half * 64 + row) * NN + col0 + c4 * 4) =
                    *(const float4*)&TOf[row * 128 + c4 * 4];
            }
        }
        return;
    }

    bool mode2 = (rowTile >= rowSplit);
    unsigned short* TO = smem;
    #pragma unroll
    for (int i = 0; i < 4; i++) {
        int rowL = wm * 64 + i * 16 + quad * 4;
        int rowG = rowTile + rowL;
        float br[4], sc[4], sh[4];
        #pragma unroll
        for (int r = 0; r < 4; r++) {
            br[r] = biasRow ? biasRow[rowG + r] : 0.0f;
            sc[r] = scale ? scale[rowG + r] : 1.0f;
            sh[r] = shift ? shift[rowG + r] : 0.0f;
        }
        #pragma unroll
        for (int j = 0; j < 4; j++) {
            int colL = wn * 64 + j * 16 + m;
            float4e c = acc[i][j];
            float v0 = ((c[0] + br[0]) * sc[0] + sh[0]) * outScale;
            float v1 = ((c[1] + br[1]) * sc[1] + sh[1]) * outScale;
            float v2 = ((c[2] + br[2]) * sc[2] + sh[2]) * outScale;
            float v3 = ((c[3] + br[3]) * sc[3] + sh[3]) * outScale;
            if (!mode2) {
                uint2 pk;
                pk.x = pack2bf(v0, v1);
                pk.y = pack2bf(v2, v3);
                *(uint2*)&TO[colL * 136 + rowL] = pk;
            } else {
                TO[(rowL + 0) * 136 + colL] = f2bf(v0);
                TO[(rowL + 1) * 136 + colL] = f2bf(v1);
                TO[(rowL + 2) * 136 + colL] = f2bf(v2);
                TO[(rowL + 3) * 136 + colL] = f2bf(v3);
            }
        }
    }
    __syncthreads();
    if (!mode2) {
        unsigned short* dst = out1 + (size_t)n * o1Batch;
        #pragma unroll
        for (int w = 0; w < 8; w++) {
            int idx = t + w * 256;
            int l = idx >> 4, ch = idx & 15;
            *(uint4*)(dst + (size_t)(col0 + l) * cs1 + rowTile + ch * 8) =
                *(const uint4*)&TO[l * 136 + ch * 8];
        }
    } else {
        unsigned short* dst = out2 + (size_t)n * o2Batch;
        int rowBase = rowTile - rowSplit;
        #pragma unroll
        for (int w = 0; w < 8; w++) {
            int idx = t + w * 256;
            int row = idx >> 4, ch = idx & 15;
            *(uint4*)(dst + (size_t)(rowBase + row) * rs2 + col0 + ch * 8) =
                *(const uint4*)&TO[row * 136 + ch * 8];
        }
    }
}

// ---------------------------------------------------------------------------
// MFMA flash attention, fixed-shift softmax, register-resident P.
// 64-q blocks (4 waves x 16 q) -> grid 1024 blocks -> 4 blocks/CU, 16 waves/CU.
// PV MFMA's k->key mapping matches P's C-layout (r8): k=quad*8+j, j<4 ->
// key=ch2*32+quad*4+j (even subtile), j>=4 -> +16 (odd subtile), so P goes
// exp2 -> pack2bf -> MFMA B-operand with zero data movement; V A-frag is two
// ds_read_b64 at matching quad*4 offsets.
// Qb: [N,L,C] bf16 (pre-scaled log2(e)/8); Kb: [N,L2,C]; Vb: [N,C,L2];
// Obf: [N,L,C] bf16 (O^T layout, feeds o-proj as B operand).
__global__ __launch_bounds__(256, 4) void attn_mfma(
    const unsigned short* __restrict__ Qb,
    const unsigned short* __restrict__ Kb,
    const unsigned short* __restrict__ Vb,
    unsigned short* __restrict__ Obf)
{
    __shared__ unsigned short Ks[128 * 72];      // K-tile [key][e], pad 8
    __shared__ unsigned short Vs[64 * 136];      // V^T-tile [e][key], pad 8

    int qb = blockIdx.x;          // 64-row q block
    int h  = blockIdx.y;
    int n  = blockIdx.z;
    int t  = threadIdx.x;
    int wave = t >> 6, lane = t & 63;
    int m = lane & 15, quad = lane >> 4;
    int l0 = qb * 64 + wave * 16;

    const unsigned short* qp = Qb + ((size_t)n * LEN + l0 + m) * CH + h * HD + quad * 8;
    short8 bQ0 = *(const short8*)qp;
    short8 bQ1 = *(const short8*)(qp + 32);

    float4e Oa[4] = {};
    float l_run = 0.0f;

    const unsigned short* KgBase = Kb + (size_t)n * LPOOL * CH + h * HD;
    const unsigned short* VgBase = Vb + ((size_t)n * CH + h * HD) * LPOOL;
    const float NEG = -17.312340f;   // -12 * log2(e)

    for (int kt = 0; kt < 8; kt++) {
        __syncthreads();   // previous iteration's readers done
        {
            const unsigned short* Kg = KgBase + (size_t)kt * 128 * CH;
            #pragma unroll
            for (int i = 0; i < 4; i++) {
                int idx = t + i * 256;
                *(uint4*)&Ks[(idx >> 3) * 72 + (idx & 7) * 8] =
                    *(const uint4*)(Kg + (size_t)(idx >> 3) * CH + (idx & 7) * 8);
            }
            const unsigned short* Vg = VgBase + kt * 128;
            #pragma unroll
            for (int i = 0; i < 4; i++) {
                int idx = t + i * 256;
                *(uint4*)&Vs[(idx >> 4) * 136 + (idx & 15) * 8] =
                    *(const uint4*)(Vg + (size_t)(idx >> 4) * LPOOL + (idx & 15) * 8);
            }
        }
        __syncthreads();

        // 4 chunks of 32 keys: QK (2 subtiles) -> exp2 -> in-register P -> PV
        #pragma unroll
        for (int ch2 = 0; ch2 < 4; ch2++) {
            const unsigned short* kpE = &Ks[(ch2 * 32 + m) * 72 + quad * 8];
            const unsigned short* kpO = kpE + 16 * 72;
            short8 aE0 = *(const short8*)kpE;
            short8 aE1 = *(const short8*)(kpE + 32);
            short8 aO0 = *(const short8*)kpO;
            short8 aO1 = *(const short8*)(kpO + 32);
            union { unsigned u[4]; short8 s; } aV[4];
            #pragma unroll
            for (int eb = 0; eb < 4; eb++) {
                const unsigned short* vp = &Vs[(eb * 16 + m) * 136 + ch2 * 32 + quad * 4];
                *(uint2*)&aV[eb].u[0] = *(const uint2*)vp;
                *(uint2*)&aV[eb].u[2] = *(const uint2*)(vp + 16);
            }

            float4e cE = {NEG, NEG, NEG, NEG};
            cE = __builtin_amdgcn_mfma_f32_16x16x32_bf16(aE0, bQ0, cE, 0, 0, 0);
            cE = __builtin_amdgcn_mfma_f32_16x16x32_bf16(aE1, bQ1, cE, 0, 0, 0);
            float4e cO = {NEG, NEG, NEG, NEG};
            cO = __builtin_amdgcn_mfma_f32_16x16x32_bf16(aO0, bQ0, cO, 0, 0, 0);
            cO = __builtin_amdgcn_mfma_f32_16x16x32_bf16(aO1, bQ1, cO, 0, 0, 0);
            float pE0 = exp2f(cE[0]), pE1 = exp2f(cE[1]);
            float pE2 = exp2f(cE[2]), pE3 = exp2f(cE[3]);
            float pO0 = exp2f(cO[0]), pO1 = exp2f(cO[1]);
            float pO2 = exp2f(cO[2]), pO3 = exp2f(cO[3]);
            l_run += ((pE0 + pE1) + (pE2 + pE3)) + ((pO0 + pO1) + (pO2 + pO3));
            union { unsigned u[4]; short8 s; } bP;
            bP.u[0] = pack2bf(pE0, pE1);
            bP.u[1] = pack2bf(pE2, pE3);
            bP.u[2] = pack2bf(pO0, pO1);
            bP.u[3] = pack2bf(pO2, pO3);
            #pragma unroll
            for (int eb = 0; eb < 4; eb++)
                Oa[eb] = __builtin_amdgcn_mfma_f32_16x16x32_bf16(aV[eb].s, bP.s, Oa[eb], 0, 0, 0);
        }
    }

    float l = l_run;
    l += __shfl_xor(l, 16);
    l += __shfl_xor(l, 32);
    float inv = 1.0f / l;
    unsigned short* op = Obf + ((size_t)n * LEN + l0 + m) * CH + h * HD;
    #pragma unroll
    for (int eb = 0; eb < 4; eb++) {
        uint2 pk;
        pk.x = pack2bf(Oa[eb][0] * inv, Oa[eb][1] * inv);
        pk.y = pack2bf(Oa[eb][2] * inv, Oa[eb][3] * inv);
        *(uint2*)(op + eb * 16 + quad * 4) = pk;
    }
}

// ---------------------------------------------------------------------------
extern "C" void kernel_launch(void* const* d_in, const int* in_sizes, int n_in,
                              void* d_out, int out_size, void* d_ws, size_t ws_size,
                              hipStream_t stream)
{
    const float* x  = (const float*)d_in[0];
    const float* Wq = (const float*)d_in[1];
    const float* bq = (const float*)d_in[2];
    const float* Wk = (const float*)d_in[3];
    const float* bk = (const float*)d_in[4];
    const float* Wv = (const float*)d_in[5];
    const float* bv = (const float*)d_in[6];
    const float* Wo = (const float*)d_in[7];
    const float* bo = (const float*)d_in[8];
    const float* Wa = (const float*)d_in[9];
    const float* g1 = (const float*)d_in[10];
    const float* b1 = (const float*)d_in[11];
    const float* m1 = (const float*)d_in[12];
    const float* v1 = (const float*)d_in[13];
    const float* g2 = (const float*)d_in[14];
    const float* b2 = (const float*)d_in[15];
    const float* m2 = (const float*)d_in[16];
    const float* v2 = (const float*)d_in[17];

    float* wsf      = (float*)d_ws;
    float* bn_scale = wsf;            // 256
    float* bn_shift = wsf + 256;      // 256
    float* bkv      = wsf + 512;      // 512
    unsigned short* Wbf   = (unsigned short*)(wsf + 1024);          // 5*65536
    unsigned short* xbf   = Wbf + 5 * 65536;                        // [N,L,C]
    unsigned short* poolT = xbf   + (size_t)NBATCH * LEN * CH;      // [N,L2,C]
    unsigned short* xabf  = poolT + (size_t)NBATCH * LPOOL * CH;    // [N,L2,C]
    unsigned short* Kbf   = xabf  + (size_t)NBATCH * LPOOL * CH;    // [N,L2,C]
    unsigned short* Vbf   = Kbf   + (size_t)NBATCH * LPOOL * CH;    // [N,C,L2]
    unsigned short* Qbf   = Vbf   + (size_t)NBATCH * LPOOL * CH;    // [N,L,C]
    unsigned short* Obf   = Qbf   + (size_t)NBATCH * LEN * CH;      // [N,L,C]

    // 1. transpose+pool over x, weights->bf16, BN affine, bkv concat
    transpool_setup<<<1345, 256, 0, stream>>>(x, xbf, poolT,
        Wq, Wk, Wv, Wo, Wa, Wbf,
        g1, b1, m1, v1, g2, b2, m2, v2, bn_scale, bn_shift, bk, bv, bkv);

    // 2. q = Wq @ x + bq, pre-scaled by log2(e)/8 -> Qbf [N,L,C]
    gemm_mfma<<<dim3(32, 2, 4), 256, 0, stream>>>(
        Wbf + 0 * 65536, xbf, (size_t)LEN * CH, bq, nullptr, nullptr,
        nullptr, 0, Qbf, (size_t)LEN * CH, 256, nullptr, 0, 0, 1 << 30,
        LEN, 0.18033688f);

    // 3. xa = BN2(BN1(Wa @ pool(x))) -> xabf [N,L2,C]
    gemm_mfma<<<dim3(8, 2, 4), 256, 0, stream>>>(
        Wbf + 4 * 65536, poolT, (size_t)LPOOL * CH, nullptr, bn_scale, bn_shift,
        nullptr, 0, xabf, (size_t)LPOOL * CH, 256, nullptr, 0, 0, 1 << 30,
        LPOOL, 1.0f);

    // 4. fused k+v: A = [Wk;Wv] (contiguous in Wbf), M=512.
    //    rows 0..255 -> Kbf [l2][c] (mode1); rows 256..511 -> Vbf [c][l2] (mode2)
    gemm_mfma<<<dim3(8, 4, 4), 256, 0, stream>>>(
        Wbf + 1 * 65536, xabf, (size_t)LPOOL * CH, bkv, nullptr, nullptr,
        nullptr, 0, Kbf, (size_t)LPOOL * CH, 256, Vbf, (size_t)LPOOL * CH, LPOOL, 256,
        LPOOL, 1.0f);

    // 5. attention -> Obf [N,L,C] bf16  (64-q blocks, grid 1024)
    attn_mfma<<<dim3(LEN / 64, NH, NBATCH), 256, 0, stream>>>(Qbf, Kbf, Vbf, Obf);

    // 6. out = Wo @ o + bo -> f32 d_out [N,C,L]
    gemm_mfma<<<dim3(32, 2, 4), 256, 0, stream>>>(
        Wbf + 3 * 65536, Obf, (size_t)LEN * CH, bo, nullptr, nullptr,
        (float*)d_out, (size_t)CH * LEN, nullptr, 0, 0, nullptr, 0, 0, 1 << 30,
        LEN, 1.0f);
}

// Round 11
// 174.949 us; speedup vs baseline: 1.3845x; 1.0406x over previous
//
#include <hip/hip_runtime.h>
#include <stdint.h>

// Problem constants
constexpr int NBATCH = 4;
constexpr int CH     = 256;   // channels
constexpr int LEN    = 4096;  // sequence length
constexpr int LPOOL  = 1024;  // pooled length (LEN/4)
constexpr int NH     = 4;     // heads
constexpr int HD     = 64;    // head dim

typedef __attribute__((ext_vector_type(8))) short short8;   // 8 bf16 in 4 VGPRs
typedef __attribute__((ext_vector_type(4))) float float4e;  // MFMA C/D

__device__ __forceinline__ unsigned short f2bf(float f) {
    union { unsigned int i; float f; } v; v.f = f;
    unsigned int lsb = (v.i >> 16) & 1u;
    v.i += 0x7fffu + lsb;
    return (unsigned short)(v.i >> 16);
}
// pack two floats -> two bf16 (round-half-up via +0x8000, then byte-perm)
__device__ __forceinline__ unsigned pack2bf(float lo, float hi) {
    unsigned a = __float_as_uint(lo) + 0x8000u;
    unsigned b = __float_as_uint(hi) + 0x8000u;
    return __builtin_amdgcn_perm(b, a, 0x07060302u);
}

// ---------------------------------------------------------------------------
// Fused: blocks 0..1023 do transpose+pool over x; blocks 1024..1343 cast the
// 5 weight matrices to bf16; block 1344 computes BN affine + bkv concat.
__global__ __launch_bounds__(256) void transpool_setup(
    const float* __restrict__ x, unsigned short* __restrict__ xbf,
    unsigned short* __restrict__ poolT,
    const float* __restrict__ w0, const float* __restrict__ w1,
    const float* __restrict__ w2, const float* __restrict__ w3,
    const float* __restrict__ w4, unsigned short* __restrict__ outW,
    const float* __restrict__ g1, const float* __restrict__ b1,
    const float* __restrict__ m1, const float* __restrict__ v1,
    const float* __restrict__ g2, const float* __restrict__ b2,
    const float* __restrict__ m2, const float* __restrict__ v2,
    float* __restrict__ scale, float* __restrict__ shift,
    const float* __restrict__ bk, const float* __restrict__ bv,
    float* __restrict__ bkv)
{
    __shared__ float T[64][65];
    __shared__ float P16[64][17];
    int b = blockIdx.x, t = threadIdx.x;
    if (b >= 1024) {
        int sb = b - 1024;
        if (sb < 320) {
            int gid = sb * 256 + t;
            int w = gid >> 14;
            int off = (gid & 16383) * 4;
            const float* src = (w == 0) ? w0 : (w == 1) ? w1 : (w == 2) ? w2 : (w == 3) ? w3 : w4;
            float4 v = *(const float4*)(src + off);
            uint2 pk;
            pk.x = pack2bf(v.x, v.y);
            pk.y = pack2bf(v.z, v.w);
            *(uint2*)(outW + w * 65536 + off) = pk;
        } else {
            float inv1 = g1[t] * rsqrtf(v1[t] + 1e-5f);
            float inv2 = g2[t] * rsqrtf(v2[t] + 1e-5f);
            scale[t] = inv1 * inv2;
            shift[t] = (b1[t] - m1[t] * inv1) * inv2 + (b2[t] - m2[t] * inv2);
            bkv[t] = bk[t];
            bkv[256 + t] = bv[t];
        }
        return;
    }
    int n = b >> 8, c0 = ((b >> 6) & 3) * 64, l0 = (b & 63) * 64;
    const float* xp = x + ((size_t)n * CH + c0) * LEN + l0;
    #pragma unroll
    for (int i = 0; i < 4; i++) {
        int idx = t + i * 256;
        int c = idx >> 4, l4 = idx & 15;
        float4 v = *(const float4*)(xp + (size_t)c * LEN + l4 * 4);
        T[c][l4 * 4 + 0] = v.x; T[c][l4 * 4 + 1] = v.y;
        T[c][l4 * 4 + 2] = v.z; T[c][l4 * 4 + 3] = v.w;
        P16[c][l4] = (v.x + v.y + v.z + v.w) * 0.25f
                   + fmaxf(fmaxf(v.x, v.y), fmaxf(v.z, v.w));
    }
    __syncthreads();
    unsigned short* op = xbf + ((size_t)n * LEN + l0) * CH + c0;
    #pragma unroll
    for (int i = 0; i < 4; i++) {
        int idx = t + i * 256;
        int l = idx >> 4, c4 = idx & 15;
        uint2 pk;
        pk.x = pack2bf(T[c4 * 4 + 0][l], T[c4 * 4 + 1][l]);
        pk.y = pack2bf(T[c4 * 4 + 2][l], T[c4 * 4 + 3][l]);
        *(uint2*)(op + (size_t)l * CH + c4 * 4) = pk;
    }
    int p0 = l0 >> 2;
    #pragma unroll
    for (int k = 0; k < 2; k++) {
        int p = (t >> 5) + k * 8;
        int c2 = (t & 31) * 2;
        unsigned pk = pack2bf(P16[c2][p], P16[c2 + 1][p]);
        *(unsigned*)(poolT + ((size_t)n * LPOOL + p0 + p) * CH + c0 + c2) = pk;
    }
}

// ---------------------------------------------------------------------------
// MFMA GEMM: D[i][j] = sum_k A[i][k] * B[j][k], K = 256 (bf16, K-contig rows).
// Epilogue: + biasRow[i]; *scale[i]+shift[i]; *outScale.
// Output modes (per 128-row tile):
//   outF != 0                : f32 [row][col] (ld NN), LDS-restaged 512B stores
//   rowTile <  rowSplit      : bf16 at out1 + col*cs1 + row  (column-major-ish)
//   rowTile >= rowSplit      : bf16 at out2 + (row-rowSplit)*rs2 + col
__global__ __launch_bounds__(256) void gemm_mfma(
    const unsigned short* __restrict__ A,
    const unsigned short* __restrict__ B, size_t bBatch,
    const float* __restrict__ biasRow,
    const float* __restrict__ scale, const float* __restrict__ shift,
    float* __restrict__ outF, size_t oFBatch,
    unsigned short* __restrict__ out1, size_t o1Batch, int cs1,
    unsigned short* __restrict__ out2, size_t o2Batch, int rs2, int rowSplit,
    int NN, float outScale)
{
    __shared__ unsigned short smem[2 * 128 * 72];  // As | Bs ; reused for epilogue
    unsigned short* As = smem;
    unsigned short* Bs = smem + 128 * 72;

    int n = blockIdx.z;
    int t = threadIdx.x;
    int wave = t >> 6, lane = t & 63, m = lane & 15, quad = lane >> 4;
    int wm = wave & 1, wn = wave >> 1;
    int rowTile = blockIdx.y * 128;
    int col0 = blockIdx.x * 128;

    const unsigned short* Ab = A + (size_t)rowTile * 256;
    const unsigned short* Bb = B + (size_t)n * bBatch + (size_t)col0 * 256;

    float4e acc[4][4] = {};

    for (int kk = 0; kk < 256; kk += 64) {
        #pragma unroll
        for (int i = 0; i < 4; i++) {
            int idx = t + i * 256;
            int row = idx >> 3, ch = idx & 7;
            *(uint4*)&As[row * 72 + ch * 8] = *(const uint4*)(Ab + (size_t)row * 256 + kk + ch * 8);
            *(uint4*)&Bs[row * 72 + ch * 8] = *(const uint4*)(Bb + (size_t)row * 256 + kk + ch * 8);
        }
        __syncthreads();
        #pragma unroll
        for (int kc = 0; kc < 2; kc++) {
            short8 af[4], bfr[4];
            #pragma unroll
            for (int i = 0; i < 4; i++)
                af[i] = *(const short8*)&As[(wm * 64 + i * 16 + m) * 72 + kc * 32 + quad * 8];
            #pragma unroll
            for (int j = 0; j < 4; j++)
                bfr[j] = *(const short8*)&Bs[(wn * 64 + j * 16 + m) * 72 + kc * 32 + quad * 8];
            #pragma unroll
            for (int i = 0; i < 4; i++)
                #pragma unroll
                for (int j = 0; j < 4; j++)
                    acc[i][j] = __builtin_amdgcn_mfma_f32_16x16x32_bf16(af[i], bfr[j], acc[i][j], 0, 0, 0);
        }
        __syncthreads();
    }

    if (outF) {
        // fp32 output, restaged through LDS in two 64-row halves
        float* TOf = (float*)smem;   // [64][128]
        float* dst = outF + (size_t)n * oFBatch;
        #pragma unroll
        for (int half = 0; half < 2; half++) {
            __syncthreads();
            if (wm == half) {
                #pragma unroll
                for (int i = 0; i < 4; i++) {
                    int rowL = i * 16 + quad * 4;
                    int rowG = rowTile + half * 64 + rowL;
                    float br[4], sc[4], sh[4];
                    #pragma unroll
                    for (int r = 0; r < 4; r++) {
                        br[r] = biasRow ? biasRow[rowG + r] : 0.0f;
                        sc[r] = scale ? scale[rowG + r] : 1.0f;
                        sh[r] = shift ? shift[rowG + r] : 0.0f;
                    }
                    #pragma unroll
                    for (int j = 0; j < 4; j++) {
                        int colL = wn * 64 + j * 16 + m;
                        float4e c = acc[i][j];
                        #pragma unroll
                        for (int r = 0; r < 4; r++)
                            TOf[(rowL + r) * 128 + colL] = ((c[r] + br[r]) * sc[r] + sh[r]) * outScale;
                    }
                }
            }
            __syncthreads();
            #pragma unroll
            for (int w = 0; w < 8; w++) {
                int idx = t + w * 256;
                int row = idx >> 5, c4 = idx & 31;
                *(float4*)(dst + (size_t)(rowTile + half * 64 + row) * NN + col0 + c4 * 4) =
                    *(const float4*)&TOf[row * 128 + c4 * 4];
            }
        }
        return;
    }

    bool mode2 = (rowTile >= rowSplit);
    unsigned short* TO = smem;
    #pragma unroll
    for (int i = 0; i < 4; i++) {
        int rowL = wm * 64 + i * 16 + quad * 4;
        int rowG = rowTile + rowL;
        float br[4], sc[4], sh[4];
        #pragma unroll
        for (int r = 0; r < 4; r++) {
            br[r] = biasRow ? biasRow[rowG + r] : 0.0f;
            sc[r] = scale ? scale[rowG + r] : 1.0f;
            sh[r] = shift ? shift[rowG + r] : 0.0f;
        }
        #pragma unroll
        for (int j = 0; j < 4; j++) {
            int colL = wn * 64 + j * 16 + m;
            float4e c = acc[i][j];
            float v0 = ((c[0] + br[0]) * sc[0] + sh[0]) * outScale;
            float v1 = ((c[1] + br[1]) * sc[1] + sh[1]) * outScale;
            float v2 = ((c[2] + br[2]) * sc[2] + sh[2]) * outScale;
            float v3 = ((c[3] + br[3]) * sc[3] + sh[3]) * outScale;
            if (!mode2) {
                uint2 pk;
                pk.x = pack2bf(v0, v1);
                pk.y = pack2bf(v2, v3);
                *(uint2*)&TO[colL * 136 + rowL] = pk;
            } else {
                TO[(rowL + 0) * 136 + colL] = f2bf(v0);
                TO[(rowL + 1) * 136 + colL] = f2bf(v1);
                TO[(rowL + 2) * 136 + colL] = f2bf(v2);
                TO[(rowL + 3) * 136 + colL] = f2bf(v3);
            }
        }
    }
    __syncthreads();
    if (!mode2) {
        unsigned short* dst = out1 + (size_t)n * o1Batch;
        #pragma unroll
        for (int w = 0; w < 8; w++) {
            int idx = t + w * 256;
            int l = idx >> 4, ch = idx & 15;
            *(uint4*)(dst + (size_t)(col0 + l) * cs1 + rowTile + ch * 8) =
                *(const uint4*)&TO[l * 136 + ch * 8];
        }
    } else {
        unsigned short* dst = out2 + (size_t)n * o2Batch;
        int rowBase = rowTile - rowSplit;
        #pragma unroll
        for (int w = 0; w < 8; w++) {
            int idx = t + w * 256;
            int row = idx >> 4, ch = idx & 15;
            *(uint4*)(dst + (size_t)(rowBase + row) * rs2 + col0 + ch * 8) =
                *(const uint4*)&TO[row * 136 + ch * 8];
        }
    }
}

// ---------------------------------------------------------------------------
// MFMA flash attention: fixed-shift softmax, register-resident P,
// 32 q/wave (128-q blocks, grid 512), DOUBLE-BUFFERED K/V LDS with register
// prefetch. __launch_bounds__(256,2) grants ~256 VGPR budget so the 32-VGPR
// prefetch doesn't spill (the r7/r9 failure). Loop: issue loads kt+1 ->
// compute kt on buf[kt&1] (loads in flight) -> ds_write buf[(kt+1)&1] ->
// one barrier. PV MFMA's k->key mapping matches P's C-layout (r8) so P goes
// exp2 -> pack2bf -> MFMA B-operand with zero data movement.
// Qb: [N,L,C] bf16 (pre-scaled log2(e)/8); Kb: [N,L2,C]; Vb: [N,C,L2];
// Obf: [N,L,C] bf16 (O^T layout, feeds o-proj as B operand).
__global__ __launch_bounds__(256, 2) void attn_mfma(
    const unsigned short* __restrict__ Qb,
    const unsigned short* __restrict__ Kb,
    const unsigned short* __restrict__ Vb,
    unsigned short* __restrict__ Obf)
{
    __shared__ unsigned short Ks[2][128 * 72];   // K-tile [key][e], pad 8
    __shared__ unsigned short Vs[2][64 * 136];   // V^T-tile [e][key], pad 8

    int qb = blockIdx.x;          // 128-row q block
    int h  = blockIdx.y;
    int n  = blockIdx.z;
    int t  = threadIdx.x;
    int wave = t >> 6, lane = t & 63;
    int m = lane & 15, quad = lane >> 4;
    int l0 = qb * 128 + wave * 32;

    const unsigned short* qp = Qb + ((size_t)n * LEN + l0 + m) * CH + h * HD + quad * 8;
    short8 bQ[2][2];
    bQ[0][0] = *(const short8*)qp;
    bQ[0][1] = *(const short8*)(qp + 32);
    bQ[1][0] = *(const short8*)(qp + 16 * CH);
    bQ[1][1] = *(const short8*)(qp + 16 * CH + 32);

    float4e Oa[2][4] = {};
    float l_run[2] = {0.0f, 0.0f};

    const unsigned short* KgBase = Kb + (size_t)n * LPOOL * CH + h * HD;
    const unsigned short* VgBase = Vb + ((size_t)n * CH + h * HD) * LPOOL;
    const float NEG = -17.312340f;   // -12 * log2(e)

    // staging indices for this thread (4 chunks each of K and V)
    int krow[4], kch[4], ve[4], vch[4];
    #pragma unroll
    for (int i = 0; i < 4; i++) {
        int idx = t + i * 256;
        krow[i] = idx >> 3; kch[i] = idx & 7;
        ve[i]   = idx >> 4; vch[i] = idx & 15;
    }

    // prefetch tile 0 into regs, write to buf 0
    uint4 kreg[4], vreg[4];
    #pragma unroll
    for (int i = 0; i < 4; i++) {
        kreg[i] = *(const uint4*)(KgBase + (size_t)krow[i] * CH + kch[i] * 8);
        vreg[i] = *(const uint4*)(VgBase + (size_t)ve[i] * LPOOL + vch[i] * 8);
    }
    #pragma unroll
    for (int i = 0; i < 4; i++) {
        *(uint4*)&Ks[0][krow[i] * 72 + kch[i] * 8] = kreg[i];
        *(uint4*)&Vs[0][ve[i] * 136 + vch[i] * 8] = vreg[i];
    }
    __syncthreads();

    for (int kt = 0; kt < 8; kt++) {
        int cur = kt & 1;
        // issue next tile's loads (results consumed after compute)
        if (kt < 7) {
            const unsigned short* Kg2 = KgBase + (size_t)(kt + 1) * 128 * CH;
            const unsigned short* Vg2 = VgBase + (kt + 1) * 128;
            #pragma unroll
            for (int i = 0; i < 4; i++) {
                kreg[i] = *(const uint4*)(Kg2 + (size_t)krow[i] * CH + kch[i] * 8);
                vreg[i] = *(const uint4*)(Vg2 + (size_t)ve[i] * LPOOL + vch[i] * 8);
            }
        }

        // compute on buf[cur]: 4 chunks of 32 keys
        #pragma unroll
        for (int ch2 = 0; ch2 < 4; ch2++) {
            const unsigned short* kpE = &Ks[cur][(ch2 * 32 + m) * 72 + quad * 8];
            const unsigned short* kpO = kpE + 16 * 72;
            short8 aE0 = *(const short8*)kpE;
            short8 aE1 = *(const short8*)(kpE + 32);
            short8 aO0 = *(const short8*)kpO;
            short8 aO1 = *(const short8*)(kpO + 32);
            union { unsigned u[4]; short8 s; } aV[4];
            #pragma unroll
            for (int eb = 0; eb < 4; eb++) {
                const unsigned short* vp = &Vs[cur][(eb * 16 + m) * 136 + ch2 * 32 + quad * 4];
                *(uint2*)&aV[eb].u[0] = *(const uint2*)vp;
                *(uint2*)&aV[eb].u[2] = *(const uint2*)(vp + 16);
            }

            #pragma unroll
            for (int qf = 0; qf < 2; qf++) {
                float4e cE = {NEG, NEG, NEG, NEG};
                cE = __builtin_amdgcn_mfma_f32_16x16x32_bf16(aE0, bQ[qf][0], cE, 0, 0, 0);
                cE = __builtin_amdgcn_mfma_f32_16x16x32_bf16(aE1, bQ[qf][1], cE, 0, 0, 0);
                float4e cO = {NEG, NEG, NEG, NEG};
                cO = __builtin_amdgcn_mfma_f32_16x16x32_bf16(aO0, bQ[qf][0], cO, 0, 0, 0);
                cO = __builtin_amdgcn_mfma_f32_16x16x32_bf16(aO1, bQ[qf][1], cO, 0, 0, 0);
                float pE0 = exp2f(cE[0]), pE1 = exp2f(cE[1]);
                float pE2 = exp2f(cE[2]), pE3 = exp2f(cE[3]);
                float pO0 = exp2f(cO[0]), pO1 = exp2f(cO[1]);
                float pO2 = exp2f(cO[2]), pO3 = exp2f(cO[3]);
                l_run[qf] += ((pE0 + pE1) + (pE2 + pE3)) + ((pO0 + pO1) + (pO2 + pO3));
                union { unsigned u[4]; short8 s; } bP;
                bP.u[0] = pack2bf(pE0, pE1);
                bP.u[1] = pack2bf(pE2, pE3);
                bP.u[2] = pack2bf(pO0, pO1);
                bP.u[3] = pack2bf(pO2, pO3);
                #pragma unroll
                for (int eb = 0; eb < 4; eb++)
                    Oa[qf][eb] = __builtin_amdgcn_mfma_f32_16x16x32_bf16(aV[eb].s, bP.s, Oa[qf][eb], 0, 0, 0);
            }
        }

        // write next tile into the other buffer; single barrier per iteration
        if (kt < 7) {
            int nxt = cur ^ 1;
            #pragma unroll
            for (int i = 0; i < 4; i++) {
                *(uint4*)&Ks[nxt][krow[i] * 72 + kch[i] * 8] = kreg[i];
                *(uint4*)&Vs[nxt][ve[i] * 136 + vch[i] * 8] = vreg[i];
            }
            __syncthreads();
        }
    }

    #pragma unroll
    for (int qf = 0; qf < 2; qf++) {
        float l = l_run[qf];
        l += __shfl_xor(l, 16);
        l += __shfl_xor(l, 32);
        float inv = 1.0f / l;
        unsigned short* op = Obf + ((size_t)n * LEN + l0 + qf * 16 + m) * CH + h * HD;
        #pragma unroll
        for (int eb = 0; eb < 4; eb++) {
            uint2 pk;
            pk.x = pack2bf(Oa[qf][eb][0] * inv, Oa[qf][eb][1] * inv);
            pk.y = pack2bf(Oa[qf][eb][2] * inv, Oa[qf][eb][3] * inv);
            *(uint2*)(op + eb * 16 + quad * 4) = pk;
        }
    }
}

// ---------------------------------------------------------------------------
extern "C" void kernel_launch(void* const* d_in, const int* in_sizes, int n_in,
                              void* d_out, int out_size, void* d_ws, size_t ws_size,
                              hipStream_t stream)
{
    const float* x  = (const float*)d_in[0];
    const float* Wq = (const float*)d_in[1];
    const float* bq = (const float*)d_in[2];
    const float* Wk = (const float*)d_in[3];
    const float* bk = (const float*)d_in[4];
    const float* Wv = (const float*)d_in[5];
    const float* bv = (const float*)d_in[6];
    const float* Wo = (const float*)d_in[7];
    const float* bo = (const float*)d_in[8];
    const float* Wa = (const float*)d_in[9];
    const float* g1 = (const float*)d_in[10];
    const float* b1 = (const float*)d_in[11];
    const float* m1 = (const float*)d_in[12];
    const float* v1 = (const float*)d_in[13];
    const float* g2 = (const float*)d_in[14];
    const float* b2 = (const float*)d_in[15];
    const float* m2 = (const float*)d_in[16];
    const float* v2 = (const float*)d_in[17];

    float* wsf      = (float*)d_ws;
    float* bn_scale = wsf;            // 256
    float* bn_shift = wsf + 256;      // 256
    float* bkv      = wsf + 512;      // 512
    unsigned short* Wbf   = (unsigned short*)(wsf + 1024);          // 5*65536
    unsigned short* xbf   = Wbf + 5 * 65536;                        // [N,L,C]
    unsigned short* poolT = xbf   + (size_t)NBATCH * LEN * CH;      // [N,L2,C]
    unsigned short* xabf  = poolT + (size_t)NBATCH * LPOOL * CH;    // [N,L2,C]
    unsigned short* Kbf   = xabf  + (size_t)NBATCH * LPOOL * CH;    // [N,L2,C]
    unsigned short* Vbf   = Kbf   + (size_t)NBATCH * LPOOL * CH;    // [N,C,L2]
    unsigned short* Qbf   = Vbf   + (size_t)NBATCH * LPOOL * CH;    // [N,L,C]
    unsigned short* Obf   = Qbf   + (size_t)NBATCH * LEN * CH;      // [N,L,C]

    // 1. transpose+pool over x, weights->bf16, BN affine, bkv concat
    transpool_setup<<<1345, 256, 0, stream>>>(x, xbf, poolT,
        Wq, Wk, Wv, Wo, Wa, Wbf,
        g1, b1, m1, v1, g2, b2, m2, v2, bn_scale, bn_shift, bk, bv, bkv);

    // 2. q = Wq @ x + bq, pre-scaled by log2(e)/8 -> Qbf [N,L,C]
    gemm_mfma<<<dim3(32, 2, 4), 256, 0, stream>>>(
        Wbf + 0 * 65536, xbf, (size_t)LEN * CH, bq, nullptr, nullptr,
        nullptr, 0, Qbf, (size_t)LEN * CH, 256, nullptr, 0, 0, 1 << 30,
        LEN, 0.18033688f);

    // 3. xa = BN2(BN1(Wa @ pool(x))) -> xabf [N,L2,C]
    gemm_mfma<<<dim3(8, 2, 4), 256, 0, stream>>>(
        Wbf + 4 * 65536, poolT, (size_t)LPOOL * CH, nullptr, bn_scale, bn_shift,
        nullptr, 0, xabf, (size_t)LPOOL * CH, 256, nullptr, 0, 0, 1 << 30,
        LPOOL, 1.0f);

    // 4. fused k+v: A = [Wk;Wv] (contiguous in Wbf), M=512.
    //    rows 0..255 -> Kbf [l2][c] (mode1); rows 256..511 -> Vbf [c][l2] (mode2)
    gemm_mfma<<<dim3(8, 4, 4), 256, 0, stream>>>(
        Wbf + 1 * 65536, xabf, (size_t)LPOOL * CH, bkv, nullptr, nullptr,
        nullptr, 0, Kbf, (size_t)LPOOL * CH, 256, Vbf, (size_t)LPOOL * CH, LPOOL, 256,
        LPOOL, 1.0f);

    // 5. attention -> Obf [N,L,C] bf16  (128-q blocks, double-buffered)
    attn_mfma<<<dim3(LEN / 128, NH, NBATCH), 256, 0, stream>>>(Qbf, Kbf, Vbf, Obf);

    // 6. out = Wo @ o + bo -> f32 d_out [N,C,L]
    gemm_mfma<<<dim3(32, 2, 4), 256, 0, stream>>>(
        Wbf + 3 * 65536, Obf, (size_t)LEN * CH, bo, nullptr, nullptr,
        (float*)d_out, (size_t)CH * LEN, nullptr, 0, 0, nullptr, 0, 0, 1 << 30,
        LEN, 1.0f);
}